// Round 2
// baseline (2815.254 us; speedup 1.0000x reference)
//
#include <hip/hip_runtime.h>
#include <math.h>
#include <float.h>

#define EPSF 1e-8f
#define EPSD 1e-8
#define D_DIM 512
#define T_DIM 1024   // 2*D (r,i interleaved)
#define K_TOP 64
#define K_KEEP 128
#define NBIN 2048
#define SEL_C 2048      // fixed chunk width; select assumes 8 vals/thread
#define CAND_SORT 512

typedef __bf16 bf16_t;
typedef __bf16 bf16x8 __attribute__((ext_vector_type(8)));
typedef __bf16 bf16x4 __attribute__((ext_vector_type(4)));
typedef float f32x4 __attribute__((ext_vector_type(4)));

// ---------------- fp64 row magnitude + bf16 normalized copy (q, from fp64 rows) ----------------
__global__ __launch_bounds__(256)
void rownorm_convert_q_kernel(const double* __restrict__ X, double* __restrict__ magd,
                              bf16_t* __restrict__ Qn, int rows) {
  int r = blockIdx.x;
  if (r >= rows) return;
  int tid = threadIdx.x;
  const double* xr = X + (size_t)r * T_DIM;
  double v[4];
  double s = 0.0;
  #pragma unroll
  for (int i = 0; i < 4; i++) { v[i] = xr[tid * 4 + i]; s += v[i] * v[i]; }
  for (int o = 32; o > 0; o >>= 1) s += __shfl_down(s, o, 64);
  __shared__ double red[4];
  __shared__ double mag_s;
  if ((tid & 63) == 0) red[tid >> 6] = s;
  __syncthreads();
  if (tid == 0) {
    double m = sqrt(red[0] + red[1] + red[2] + red[3] + EPSD);
    magd[r] = m; mag_s = m;
  }
  __syncthreads();
  double inv = 1.0 / mag_s;
  bf16x4 o;
  #pragma unroll
  for (int i = 0; i < 4; i++) o[i] = (bf16_t)((float)(v[i] * inv));
  *(bf16x4*)(Qn + (size_t)r * T_DIM + tid * 4) = o;
}

// ---------------- fp64 row magnitude + bf16 normalized copy (keys, from fp32 rows) ----------------
__global__ __launch_bounds__(256)
void rownorm_convert_k_kernel(const float* __restrict__ X, double* __restrict__ magd,
                              bf16_t* __restrict__ Kn, int rows) {
  int r = blockIdx.x;
  if (r >= rows) return;
  int tid = threadIdx.x;
  float4 v = ((const float4*)(X + (size_t)r * T_DIM))[tid];
  double s = (double)v.x * v.x + (double)v.y * v.y + (double)v.z * v.z + (double)v.w * v.w;
  for (int o = 32; o > 0; o >>= 1) s += __shfl_down(s, o, 64);
  __shared__ double red[4];
  __shared__ float inv_s;
  if ((tid & 63) == 0) red[tid >> 6] = s;
  __syncthreads();
  if (tid == 0) {
    double m = sqrt(red[0] + red[1] + red[2] + red[3] + EPSD);
    magd[r] = m; inv_s = (float)(1.0 / m);
  }
  __syncthreads();
  float inv = inv_s;
  bf16x4 o;
  o[0] = (bf16_t)(v.x * inv); o[1] = (bf16_t)(v.y * inv);
  o[2] = (bf16_t)(v.z * inv); o[3] = (bf16_t)(v.w * inv);
  *(bf16x4*)(Kn + (size_t)r * T_DIM + tid * 4) = o;
}

// ---------------- fp64-accumulate complex linear (query projection) ----------------
__global__ __launch_bounds__(256)
void cgemm_f64_kernel(const float* __restrict__ X,
                      const float* __restrict__ Wr, const float* __restrict__ Wi,
                      const float* __restrict__ br, const float* __restrict__ bi,
                      double* __restrict__ Yd, int M) {
  __shared__ float Ar[16][64], Ai[16][64], Br_[16][64], Bi_[16][64];
  int tid = threadIdx.x;
  int tx = tid & 15, ty = tid >> 4;
  int m0 = blockIdx.x * 64, n0 = blockIdx.y * 64;
  double accR[4][4] = {{0}}, accI[4][4] = {{0}};
  for (int k0 = 0; k0 < D_DIM; k0 += 16) {
    #pragma unroll
    for (int gi = 0; gi < 2; gi++) {
      int g = tid + gi * 256;
      int m = g >> 3, dg = g & 7;
      float4 v = *(const float4*)(X + (size_t)(m0 + m) * T_DIM + 2 * k0 + dg * 4);
      Ar[dg*2][m] = v.x; Ai[dg*2][m] = v.y; Ar[dg*2+1][m] = v.z; Ai[dg*2+1][m] = v.w;
    }
    {
      int j = tid >> 2, c = tid & 3;
      float4 vr = *(const float4*)(Wr + (size_t)(n0 + j) * D_DIM + k0 + c * 4);
      float4 vi = *(const float4*)(Wi + (size_t)(n0 + j) * D_DIM + k0 + c * 4);
      Br_[c*4+0][j] = vr.x; Br_[c*4+1][j] = vr.y; Br_[c*4+2][j] = vr.z; Br_[c*4+3][j] = vr.w;
      Bi_[c*4+0][j] = vi.x; Bi_[c*4+1][j] = vi.y; Bi_[c*4+2][j] = vi.z; Bi_[c*4+3][j] = vi.w;
    }
    __syncthreads();
    #pragma unroll
    for (int k = 0; k < 16; k++) {
      float arr[4], aii[4], wrr[4], wii[4];
      *(float4*)arr = *(const float4*)&Ar[k][ty*4];
      *(float4*)aii = *(const float4*)&Ai[k][ty*4];
      *(float4*)wrr = *(const float4*)&Br_[k][tx*4];
      *(float4*)wii = *(const float4*)&Bi_[k][tx*4];
      #pragma unroll
      for (int im = 0; im < 4; im++)
        #pragma unroll
        for (int jn = 0; jn < 4; jn++) {
          double ar = (double)arr[im], ai = (double)aii[im];
          double wr = (double)wrr[jn], wi = (double)wii[jn];
          accR[im][jn] += ar * wr - ai * wi;
          accI[im][jn] += ar * wi + ai * wr;
        }
    }
    __syncthreads();
  }
  #pragma unroll
  for (int im = 0; im < 4; im++) {
    int m = m0 + ty * 4 + im;
    #pragma unroll
    for (int jn = 0; jn < 4; jn++) {
      int j = n0 + tx * 4 + jn;
      size_t base = (size_t)m * T_DIM + j * 2;
      Yd[base]     = accR[im][jn] + (double)br[j];
      Yd[base + 1] = accI[im][jn] + (double)bi[j];
    }
  }
}

// ---------------- fp32 complex linear (output projection) ----------------
__global__ __launch_bounds__(256)
void cgemm_kernel(const float* __restrict__ X,
                  const float* __restrict__ Wr, const float* __restrict__ Wi,
                  const float* __restrict__ br, const float* __restrict__ bi,
                  float* __restrict__ Y, int M) {
  __shared__ float Ar[16][64], Ai[16][64], Br_[16][64], Bi_[16][64];
  int tid = threadIdx.x;
  int tx = tid & 15, ty = tid >> 4;
  int m0 = blockIdx.x * 64, n0 = blockIdx.y * 64;
  float accR[4][4] = {{0}}, accI[4][4] = {{0}};
  for (int k0 = 0; k0 < D_DIM; k0 += 16) {
    #pragma unroll
    for (int gi = 0; gi < 2; gi++) {
      int g = tid + gi * 256;
      int m = g >> 3, dg = g & 7;
      float4 v = *(const float4*)(X + (size_t)(m0 + m) * T_DIM + 2 * k0 + dg * 4);
      Ar[dg*2][m] = v.x; Ai[dg*2][m] = v.y; Ar[dg*2+1][m] = v.z; Ai[dg*2+1][m] = v.w;
    }
    {
      int j = tid >> 2, c = tid & 3;
      float4 vr = *(const float4*)(Wr + (size_t)(n0 + j) * D_DIM + k0 + c * 4);
      float4 vi = *(const float4*)(Wi + (size_t)(n0 + j) * D_DIM + k0 + c * 4);
      Br_[c*4+0][j] = vr.x; Br_[c*4+1][j] = vr.y; Br_[c*4+2][j] = vr.z; Br_[c*4+3][j] = vr.w;
      Bi_[c*4+0][j] = vi.x; Bi_[c*4+1][j] = vi.y; Bi_[c*4+2][j] = vi.z; Bi_[c*4+3][j] = vi.w;
    }
    __syncthreads();
    #pragma unroll
    for (int k = 0; k < 16; k++) {
      float arr[4], aii[4], wrr[4], wii[4];
      *(float4*)arr = *(const float4*)&Ar[k][ty*4];
      *(float4*)aii = *(const float4*)&Ai[k][ty*4];
      *(float4*)wrr = *(const float4*)&Br_[k][tx*4];
      *(float4*)wii = *(const float4*)&Bi_[k][tx*4];
      #pragma unroll
      for (int im = 0; im < 4; im++)
        #pragma unroll
        for (int jn = 0; jn < 4; jn++) {
          accR[im][jn] += arr[im] * wrr[jn] - aii[im] * wii[jn];
          accI[im][jn] += arr[im] * wii[jn] + aii[im] * wrr[jn];
        }
    }
    __syncthreads();
  }
  #pragma unroll
  for (int im = 0; im < 4; im++) {
    int m = m0 + ty * 4 + im;
    #pragma unroll
    for (int jn = 0; jn < 4; jn++) {
      int j = n0 + tx * 4 + jn;
      float2 o; o.x = accR[im][jn] + br[j]; o.y = accI[im][jn] + bi[j];
      *(float2*)(Y + (size_t)m * T_DIM + j * 2) = o;
    }
  }
}

// ---------------- bf16 MFMA filter scores: S[m][c] = dot(Qn[m], Kn[n_off+c]) ----------------
// 128x128 tile, BK=32, 16x16x32 MFMA, global_load_lds width=16 (m97 structure).
// Output stored bf16 (selection only needs bf16-level precision; exact rescore follows).
__global__ __launch_bounds__(256)
void mfma_score_kernel(const bf16_t* __restrict__ Qn, const bf16_t* __restrict__ Kn,
                       bf16_t* __restrict__ S, int n_off, int C) {
  __shared__ bf16_t As[128 * 32];   // row-major [128][32], 64B/row
  __shared__ bf16_t Bs[128 * 32];
  int tid = threadIdx.x;
  int lane = tid & 63, wv = tid >> 6;
  int m0 = blockIdx.x * 128;
  int n0 = blockIdx.y * 128;                 // within chunk
  int wm = (wv & 1) * 64, wn = (wv >> 1) * 64;
  f32x4 acc[4][4] = {};
  const bf16_t* Ag = Qn + (size_t)m0 * T_DIM;
  const bf16_t* Bg = Kn + (size_t)(n_off + n0) * T_DIM;
  int frow = lane & 15;
  int fk = (lane >> 4) * 8;
  for (int k0 = 0; k0 < T_DIM; k0 += 32) {
    #pragma unroll
    for (int it = 0; it < 2; it++) {
      int rbase = (it * 4 + wv) * 16;
      int row = rbase + (lane >> 2);
      int gcol = lane & 3;
      const bf16_t* gpa = Ag + (size_t)row * T_DIM + k0 + gcol * 8;
      const bf16_t* gpb = Bg + (size_t)row * T_DIM + k0 + gcol * 8;
      bf16_t* lpa = As + rbase * 32 + lane * 8;
      bf16_t* lpb = Bs + rbase * 32 + lane * 8;
      __builtin_amdgcn_global_load_lds(
          (const __attribute__((address_space(1))) void*)gpa,
          (__attribute__((address_space(3))) void*)lpa, 16, 0, 0);
      __builtin_amdgcn_global_load_lds(
          (const __attribute__((address_space(1))) void*)gpb,
          (__attribute__((address_space(3))) void*)lpb, 16, 0, 0);
    }
    __syncthreads();
    bf16x8 a[4], b[4];
    #pragma unroll
    for (int i = 0; i < 4; i++)
      a[i] = *(const bf16x8*)(As + (wm + i * 16 + frow) * 32 + fk);
    #pragma unroll
    for (int j = 0; j < 4; j++)
      b[j] = *(const bf16x8*)(Bs + (wn + j * 16 + frow) * 32 + fk);
    #pragma unroll
    for (int i = 0; i < 4; i++)
      #pragma unroll
      for (int j = 0; j < 4; j++)
        acc[i][j] = __builtin_amdgcn_mfma_f32_16x16x32_bf16(a[i], b[j], acc[i][j], 0, 0, 0);
    __syncthreads();
  }
  // C/D layout: row = (lane>>4)*4 + reg, col = lane&15  (m89/m91-verified)
  int col = lane & 15, qr = (lane >> 4) * 4;
  #pragma unroll
  for (int i = 0; i < 4; i++)
    #pragma unroll
    for (int j = 0; j < 4; j++) {
      int n = n0 + wn + j * 16 + col;
      #pragma unroll
      for (int r = 0; r < 4; r++) {
        int m = m0 + wm + i * 16 + qr + r;
        S[(size_t)m * C + n] = (bf16_t)acc[i][j][r];
      }
    }
}

// ---------------- exact per-chunk top-128 via two-level histogram threshold ----------------
// One pass over the row (held in registers), parallel suffix-scan boundary find,
// 22-bit-effective threshold => collected set ~= 128 + ties; tiny bitonic sort.
__global__ __launch_bounds__(256)
void select_kernel(const bf16_t* __restrict__ S, int key_off,
                   int slot_off, int nslot,
                   float* __restrict__ cand_v, int* __restrict__ cand_i) {
  int q = blockIdx.x, tid = threadIdx.x;
  __shared__ unsigned hist[NBIN];
  __shared__ unsigned psum[256];
  __shared__ float bv[CAND_SORT];
  __shared__ int bi[CAND_SORT];
  __shared__ unsigned binB_s, cntGt_s, binB2_s, cnt_s;

  // load 8 bf16 values per thread (one 16B load), keep in registers
  bf16x8 v8 = ((const bf16x8*)(S + (size_t)q * SEL_C))[tid];
  float f[8]; unsigned u[8];
  #pragma unroll
  for (int i = 0; i < 8; i++) {
    float x = (float)v8[i];
    f[i] = x;
    unsigned t = __float_as_uint(x);
    u[i] = (t & 0x80000000u) ? ~t : (t | 0x80000000u);   // monotone order-preserving map
  }
  for (int i = tid; i < NBIN; i += 256) hist[i] = 0;
  if (tid == 0) { cnt_s = 0; binB_s = 0; cntGt_s = 0; binB2_s = 0; }
  __syncthreads();
  // coarse histogram: top 11 bits
  #pragma unroll
  for (int i = 0; i < 8; i++) atomicAdd(&hist[u[i] >> 21], 1u);
  __syncthreads();
  // parallel suffix scan: psum[t] = sum of hist over groups t..255 (8 bins/group)
  unsigned sgrp = 0;
  #pragma unroll
  for (int b = 0; b < 8; b++) sgrp += hist[tid * 8 + b];
  psum[tid] = sgrp;
  __syncthreads();
  for (int off = 1; off < 256; off <<= 1) {
    unsigned v = psum[tid];
    unsigned add = (tid + off < 256) ? psum[tid + off] : 0u;
    __syncthreads();
    psum[tid] = v + add;
    __syncthreads();
  }
  if (psum[tid] >= (unsigned)K_KEEP && (tid == 255 || psum[tid + 1] < (unsigned)K_KEEP)) {
    unsigned acc = (tid == 255) ? 0u : psum[tid + 1];
    for (int b = tid * 8 + 7; b >= tid * 8; b--) {
      unsigned h = hist[b];
      if (acc + h >= (unsigned)K_KEEP) { binB_s = (unsigned)b; cntGt_s = acc; break; }
      acc += h;
    }
  }
  __syncthreads();
  unsigned B = binB_s;
  unsigned K2 = (unsigned)K_KEEP - cntGt_s;   // >=1 by construction
  // refined histogram on boundary bin: next 11 bits (captures full bf16 precision)
  for (int i = tid; i < NBIN; i += 256) hist[i] = 0;
  __syncthreads();
  #pragma unroll
  for (int i = 0; i < 8; i++)
    if ((u[i] >> 21) == B) atomicAdd(&hist[(u[i] >> 10) & 2047u], 1u);
  __syncthreads();
  unsigned sgrp2 = 0;
  #pragma unroll
  for (int b = 0; b < 8; b++) sgrp2 += hist[tid * 8 + b];
  psum[tid] = sgrp2;
  __syncthreads();
  for (int off = 1; off < 256; off <<= 1) {
    unsigned v = psum[tid];
    unsigned add = (tid + off < 256) ? psum[tid + off] : 0u;
    __syncthreads();
    psum[tid] = v + add;
    __syncthreads();
  }
  if (psum[tid] >= K2 && (tid == 255 || psum[tid + 1] < K2)) {
    unsigned acc = (tid == 255) ? 0u : psum[tid + 1];
    for (int b = tid * 8 + 7; b >= tid * 8; b--) {
      unsigned h = hist[b];
      if (acc + h >= K2) { binB2_s = (unsigned)b; break; }
      acc += h;
    }
  }
  __syncthreads();
  unsigned B2 = binB2_s;
  // collect: guaranteed >= K_KEEP kept, typically ~K_KEEP + a few ties
  #pragma unroll
  for (int i = 0; i < 8; i++) {
    unsigned bin = u[i] >> 21;
    bool keep = (bin > B) || (bin == B && ((u[i] >> 10) & 2047u) >= B2);
    if (keep) {
      unsigned p = atomicAdd(&cnt_s, 1u);
      if (p < (unsigned)CAND_SORT) { bv[p] = f[i]; bi[p] = key_off + tid * 8 + i; }
    }
  }
  __syncthreads();
  int cnt = (int)min(cnt_s, (unsigned)CAND_SORT);
  int n = K_KEEP; while (n < cnt) n <<= 1;
  for (int x = cnt + tid; x < n; x += 256) { bv[x] = -FLT_MAX; bi[x] = 0x7FFFFFFF; }
  for (int k = 2; k <= n; k <<= 1) {
    for (int j = k >> 1; j > 0; j >>= 1) {
      __syncthreads();
      for (int i = tid; i < n; i += 256) {
        int ixj = i ^ j;
        if (ixj > i) {
          float a = bv[i], b = bv[ixj];
          int ia = bi[i], ib = bi[ixj];
          bool a_worse = (a < b) || (a == b && ia > ib);
          bool up = ((i & k) == 0);
          if (up ? a_worse : !a_worse) {
            bv[i] = b; bv[ixj] = a; bi[i] = ib; bi[ixj] = ia;
          }
        }
      }
    }
  }
  __syncthreads();
  if (tid < K_KEEP) {
    cand_v[(size_t)q * nslot + slot_off + tid] = bv[tid];
    cand_i[(size_t)q * nslot + slot_off + tid] = bi[tid];
  }
}

// ---------------- merge per-chunk candidate lists -> global top-128 indices ----------------
__global__ __launch_bounds__(256)
void merge_kernel(const float* __restrict__ cand_v, const int* __restrict__ cand_i,
                  int nslot, int* __restrict__ topi) {
  int q = blockIdx.x, tid = threadIdx.x;
  __shared__ float bv[NBIN];
  __shared__ int bi[NBIN];
  int n = K_KEEP; while (n < nslot) n <<= 1;
  for (int i = tid; i < n; i += 256) {
    if (i < nslot) { bv[i] = cand_v[(size_t)q * nslot + i]; bi[i] = cand_i[(size_t)q * nslot + i]; }
    else { bv[i] = -FLT_MAX; bi[i] = 0x7FFFFFFF; }
  }
  for (int k = 2; k <= n; k <<= 1) {
    for (int j = k >> 1; j > 0; j >>= 1) {
      __syncthreads();
      for (int i = tid; i < n; i += 256) {
        int ixj = i ^ j;
        if (ixj > i) {
          float a = bv[i], b = bv[ixj];
          int ia = bi[i], ib = bi[ixj];
          bool a_worse = (a < b) || (a == b && ia > ib);
          bool up = ((i & k) == 0);
          if (up ? a_worse : !a_worse) {
            bv[i] = b; bv[ixj] = a; bi[i] = ib; bi[ixj] = ia;
          }
        }
      }
    }
  }
  __syncthreads();
  if (tid < K_KEEP) topi[q * K_KEEP + tid] = bi[tid];
}

// ---------------- fp64 exact rescore + top-64 + softmax + gather + phase_norm ----------------
__global__ __launch_bounds__(256)
void rescore_kernel(const int* __restrict__ topi,
                    const double* __restrict__ Qd,
                    const double* __restrict__ qmagd, const double* __restrict__ kmagd,
                    const float* __restrict__ Kk, const float* __restrict__ V,
                    const float* __restrict__ gamma,
                    float* __restrict__ XN) {
  int q = blockIdx.x, tid = threadIdx.x;
  __shared__ double qrow[T_DIM];
  __shared__ double cval[K_KEEP];
  __shared__ int cidx[K_KEEP];
  __shared__ float w[K_TOP];
  __shared__ int widx[K_TOP];
  __shared__ float red[4];
  for (int i = tid; i < T_DIM / 2; i += 256)
    ((double2*)qrow)[i] = ((const double2*)(Qd + (size_t)q * T_DIM))[i];
  if (tid < K_KEEP) cidx[tid] = topi[q * K_KEEP + tid];
  __syncthreads();
  double qm = qmagd[q];
  int wv = tid >> 6, ln = tid & 63;
  for (int c = wv; c < K_KEEP; c += 4) {
    int key = cidx[c];
    const float4* kr4 = (const float4*)(Kk + (size_t)key * T_DIM);
    double s = 0.0;
    #pragma unroll
    for (int it = 0; it < 4; it++) {
      float4 v = kr4[ln + it * 64];
      int t = (ln + it * 64) * 4;
      s += (double)v.x * qrow[t]     + (double)v.y * qrow[t + 1]
         + (double)v.z * qrow[t + 2] + (double)v.w * qrow[t + 3];
    }
    for (int o = 32; o > 0; o >>= 1) s += __shfl_down(s, o, 64);
    if (ln == 0) cval[c] = s / (qm * kmagd[key] + EPSD);
  }
  __syncthreads();
  for (int k = 2; k <= K_KEEP; k <<= 1) {
    for (int j = k >> 1; j > 0; j >>= 1) {
      __syncthreads();
      if (tid < K_KEEP) {
        int i = tid, ixj = i ^ j;
        if (ixj > i) {
          double a = cval[i], b = cval[ixj];
          int ia = cidx[i], ib = cidx[ixj];
          bool a_worse = (a < b) || (a == b && ia > ib);
          bool up = ((i & k) == 0);
          if (up ? a_worse : !a_worse) {
            cval[i] = b; cval[ixj] = a; cidx[i] = ib; cidx[ixj] = ia;
          }
        }
      }
    }
  }
  __syncthreads();
  if (tid < 64) {
    double v = cval[tid];
    double m = cval[0];
    double e = exp(v - m);
    double s = e;
    for (int o = 32; o > 0; o >>= 1) s += __shfl_down(s, o, 64);
    s = __shfl(s, 0, 64);
    w[tid] = (float)(e / s);
    widx[tid] = cidx[tid];
  }
  __syncthreads();
  float4 acc = {0.f, 0.f, 0.f, 0.f};
  #pragma unroll 4
  for (int j2 = 0; j2 < 64; j2++) {
    float wj = w[j2];
    float4 v = *(const float4*)(V + (size_t)widx[j2] * T_DIM + tid * 4);
    acc.x += wj * v.x; acc.y += wj * v.y; acc.z += wj * v.z; acc.w += wj * v.w;
  }
  float ls = acc.x*acc.x + acc.y*acc.y + acc.z*acc.z + acc.w*acc.w;
  for (int o = 32; o > 0; o >>= 1) ls += __shfl_down(ls, o, 64);
  if ((tid & 63) == 0) red[tid >> 6] = ls;
  __syncthreads();
  float tot = red[0] + red[1] + red[2] + red[3];
  float rms = sqrtf(tot / (float)D_DIM + EPSF);
  float g0 = gamma[tid * 2] / rms, g1 = gamma[tid * 2 + 1] / rms;
  float4 o = { acc.x * g0, acc.y * g0, acc.z * g1, acc.w * g1 };
  *(float4*)(XN + (size_t)q * T_DIM + tid * 4) = o;
}

extern "C" void kernel_launch(void* const* d_in, const int* in_sizes, int n_in,
                              void* d_out, int out_size, void* d_ws, size_t ws_size,
                              hipStream_t stream) {
  const float* query  = (const float*)d_in[0];
  const float* keys   = (const float*)d_in[1];
  const float* values = (const float*)d_in[2];
  const float* Wq_r   = (const float*)d_in[3];
  const float* Wq_i   = (const float*)d_in[4];
  const float* bq_r   = (const float*)d_in[5];
  const float* bq_i   = (const float*)d_in[6];
  const float* Wo_r   = (const float*)d_in[7];
  const float* Wo_i   = (const float*)d_in[8];
  const float* bo_r   = (const float*)d_in[9];
  const float* bo_i   = (const float*)d_in[10];
  const float* gamma  = (const float*)d_in[11];
  float* out = (float*)d_out;

  int M = in_sizes[0] / T_DIM;   // 4096
  int N = in_sizes[1] / T_DIM;   // 32768

  char* ws = (char*)d_ws;
  size_t off = 0;
  double* qd    = (double*)(ws + off); off += (size_t)M * T_DIM * 8;
  float*  xn    = (float*) (ws + off); off += (size_t)M * T_DIM * 4;
  double* qmagd = (double*)(ws + off); off += (size_t)M * 8;
  double* kmagd = (double*)(ws + off); off += (size_t)N * 8;
  int*    topi  = (int*)   (ws + off); off += (size_t)M * K_KEEP * 4;
  float*  candv = (float*) (ws + off); off += (size_t)M * NBIN * 4;
  int*    candi = (int*)   (ws + off); off += (size_t)M * NBIN * 4;
  bf16_t* qn    = (bf16_t*)(ws + off); off += (size_t)M * T_DIM * 2;
  bf16_t* kn    = (bf16_t*)(ws + off); off += (size_t)N * T_DIM * 2;
  bf16_t* sc    = (bf16_t*)(ws + off); off += (size_t)M * SEL_C * 2;

  int C = SEL_C;                 // fixed 2048 (select kernel is specialized)
  int nchunks = N / C;           // 16
  int nslot = nchunks * K_KEEP;  // 2048

  dim3 blk(256);
  cgemm_f64_kernel<<<dim3(M / 64, D_DIM / 64), blk, 0, stream>>>(query, Wq_r, Wq_i, bq_r, bq_i, qd, M);
  rownorm_convert_q_kernel<<<dim3(M), blk, 0, stream>>>(qd, qmagd, qn, M);
  rownorm_convert_k_kernel<<<dim3(N), blk, 0, stream>>>(keys, kmagd, kn, N);
  for (int c = 0; c < nchunks; c++) {
    int noff = c * C;
    mfma_score_kernel<<<dim3(M / 128, C / 128), blk, 0, stream>>>(qn, kn, sc, noff, C);
    select_kernel<<<dim3(M), blk, 0, stream>>>(sc, noff, c * K_KEEP, nslot, candv, candi);
  }
  merge_kernel<<<dim3(M), blk, 0, stream>>>(candv, candi, nslot, topi);
  rescore_kernel<<<dim3(M), blk, 0, stream>>>(topi, qd, qmagd, kmagd, keys, values, gamma, xn);
  cgemm_kernel<<<dim3(M / 64, D_DIM / 64), blk, 0, stream>>>(xn, Wo_r, Wo_i, bo_r, bo_i, out, M);
}

// Round 3
// 1867.293 us; speedup vs baseline: 1.5077x; 1.5077x over previous
//
#include <hip/hip_runtime.h>
#include <math.h>
#include <float.h>

#define EPSF 1e-8f
#define EPSD 1e-8
#define D_DIM 512
#define T_DIM 1024   // 2*D (r,i interleaved)
#define K_TOP 64
#define K_KEEP 128
#define NBIN 2048
#define CAND_SORT 1024

typedef __bf16 bf16_t;
typedef __bf16 bf16x8 __attribute__((ext_vector_type(8)));
typedef __bf16 bf16x4 __attribute__((ext_vector_type(4)));
typedef float f32x4 __attribute__((ext_vector_type(4)));

// ---------------- fp64 row magnitude + bf16 normalized copy (q, from fp64 rows) ----------------
__global__ __launch_bounds__(256)
void rownorm_convert_q_kernel(const double* __restrict__ X, double* __restrict__ magd,
                              bf16_t* __restrict__ Qn, int rows) {
  int r = blockIdx.x;
  if (r >= rows) return;
  int tid = threadIdx.x;
  const double* xr = X + (size_t)r * T_DIM;
  double v[4];
  double s = 0.0;
  #pragma unroll
  for (int i = 0; i < 4; i++) { v[i] = xr[tid * 4 + i]; s += v[i] * v[i]; }
  for (int o = 32; o > 0; o >>= 1) s += __shfl_down(s, o, 64);
  __shared__ double red[4];
  __shared__ double mag_s;
  if ((tid & 63) == 0) red[tid >> 6] = s;
  __syncthreads();
  if (tid == 0) {
    double m = sqrt(red[0] + red[1] + red[2] + red[3] + EPSD);
    magd[r] = m; mag_s = m;
  }
  __syncthreads();
  double inv = 1.0 / mag_s;
  bf16x4 o;
  #pragma unroll
  for (int i = 0; i < 4; i++) o[i] = (bf16_t)((float)(v[i] * inv));
  *(bf16x4*)(Qn + (size_t)r * T_DIM + tid * 4) = o;
}

// ---------------- fp64 row magnitude + bf16 normalized copy (keys, from fp32 rows) ----------------
__global__ __launch_bounds__(256)
void rownorm_convert_k_kernel(const float* __restrict__ X, double* __restrict__ magd,
                              bf16_t* __restrict__ Kn, int rows) {
  int r = blockIdx.x;
  if (r >= rows) return;
  int tid = threadIdx.x;
  float4 v = ((const float4*)(X + (size_t)r * T_DIM))[tid];
  double s = (double)v.x * v.x + (double)v.y * v.y + (double)v.z * v.z + (double)v.w * v.w;
  for (int o = 32; o > 0; o >>= 1) s += __shfl_down(s, o, 64);
  __shared__ double red[4];
  __shared__ float inv_s;
  if ((tid & 63) == 0) red[tid >> 6] = s;
  __syncthreads();
  if (tid == 0) {
    double m = sqrt(red[0] + red[1] + red[2] + red[3] + EPSD);
    magd[r] = m; inv_s = (float)(1.0 / m);
  }
  __syncthreads();
  float inv = inv_s;
  bf16x4 o;
  o[0] = (bf16_t)(v.x * inv); o[1] = (bf16_t)(v.y * inv);
  o[2] = (bf16_t)(v.z * inv); o[3] = (bf16_t)(v.w * inv);
  *(bf16x4*)(Kn + (size_t)r * T_DIM + tid * 4) = o;
}

// ---------------- fp64-accumulate complex linear (query projection) ----------------
__global__ __launch_bounds__(256)
void cgemm_f64_kernel(const float* __restrict__ X,
                      const float* __restrict__ Wr, const float* __restrict__ Wi,
                      const float* __restrict__ br, const float* __restrict__ bi,
                      double* __restrict__ Yd, int M) {
  __shared__ float Ar[16][64], Ai[16][64], Br_[16][64], Bi_[16][64];
  int tid = threadIdx.x;
  int tx = tid & 15, ty = tid >> 4;
  int m0 = blockIdx.x * 64, n0 = blockIdx.y * 64;
  double accR[4][4] = {{0}}, accI[4][4] = {{0}};
  for (int k0 = 0; k0 < D_DIM; k0 += 16) {
    #pragma unroll
    for (int gi = 0; gi < 2; gi++) {
      int g = tid + gi * 256;
      int m = g >> 3, dg = g & 7;
      float4 v = *(const float4*)(X + (size_t)(m0 + m) * T_DIM + 2 * k0 + dg * 4);
      Ar[dg*2][m] = v.x; Ai[dg*2][m] = v.y; Ar[dg*2+1][m] = v.z; Ai[dg*2+1][m] = v.w;
    }
    {
      int j = tid >> 2, c = tid & 3;
      float4 vr = *(const float4*)(Wr + (size_t)(n0 + j) * D_DIM + k0 + c * 4);
      float4 vi = *(const float4*)(Wi + (size_t)(n0 + j) * D_DIM + k0 + c * 4);
      Br_[c*4+0][j] = vr.x; Br_[c*4+1][j] = vr.y; Br_[c*4+2][j] = vr.z; Br_[c*4+3][j] = vr.w;
      Bi_[c*4+0][j] = vi.x; Bi_[c*4+1][j] = vi.y; Bi_[c*4+2][j] = vi.z; Bi_[c*4+3][j] = vi.w;
    }
    __syncthreads();
    #pragma unroll
    for (int k = 0; k < 16; k++) {
      float arr[4], aii[4], wrr[4], wii[4];
      *(float4*)arr = *(const float4*)&Ar[k][ty*4];
      *(float4*)aii = *(const float4*)&Ai[k][ty*4];
      *(float4*)wrr = *(const float4*)&Br_[k][tx*4];
      *(float4*)wii = *(const float4*)&Bi_[k][tx*4];
      #pragma unroll
      for (int im = 0; im < 4; im++)
        #pragma unroll
        for (int jn = 0; jn < 4; jn++) {
          double ar = (double)arr[im], ai = (double)aii[im];
          double wr = (double)wrr[jn], wi = (double)wii[jn];
          accR[im][jn] += ar * wr - ai * wi;
          accI[im][jn] += ar * wi + ai * wr;
        }
    }
    __syncthreads();
  }
  #pragma unroll
  for (int im = 0; im < 4; im++) {
    int m = m0 + ty * 4 + im;
    #pragma unroll
    for (int jn = 0; jn < 4; jn++) {
      int j = n0 + tx * 4 + jn;
      size_t base = (size_t)m * T_DIM + j * 2;
      Yd[base]     = accR[im][jn] + (double)br[j];
      Yd[base + 1] = accI[im][jn] + (double)bi[j];
    }
  }
}

// ---------------- fp32 complex linear (output projection) ----------------
__global__ __launch_bounds__(256)
void cgemm_kernel(const float* __restrict__ X,
                  const float* __restrict__ Wr, const float* __restrict__ Wi,
                  const float* __restrict__ br, const float* __restrict__ bi,
                  float* __restrict__ Y, int M) {
  __shared__ float Ar[16][64], Ai[16][64], Br_[16][64], Bi_[16][64];
  int tid = threadIdx.x;
  int tx = tid & 15, ty = tid >> 4;
  int m0 = blockIdx.x * 64, n0 = blockIdx.y * 64;
  float accR[4][4] = {{0}}, accI[4][4] = {{0}};
  for (int k0 = 0; k0 < D_DIM; k0 += 16) {
    #pragma unroll
    for (int gi = 0; gi < 2; gi++) {
      int g = tid + gi * 256;
      int m = g >> 3, dg = g & 7;
      float4 v = *(const float4*)(X + (size_t)(m0 + m) * T_DIM + 2 * k0 + dg * 4);
      Ar[dg*2][m] = v.x; Ai[dg*2][m] = v.y; Ar[dg*2+1][m] = v.z; Ai[dg*2+1][m] = v.w;
    }
    {
      int j = tid >> 2, c = tid & 3;
      float4 vr = *(const float4*)(Wr + (size_t)(n0 + j) * D_DIM + k0 + c * 4);
      float4 vi = *(const float4*)(Wi + (size_t)(n0 + j) * D_DIM + k0 + c * 4);
      Br_[c*4+0][j] = vr.x; Br_[c*4+1][j] = vr.y; Br_[c*4+2][j] = vr.z; Br_[c*4+3][j] = vr.w;
      Bi_[c*4+0][j] = vi.x; Bi_[c*4+1][j] = vi.y; Bi_[c*4+2][j] = vi.z; Bi_[c*4+3][j] = vi.w;
    }
    __syncthreads();
    #pragma unroll
    for (int k = 0; k < 16; k++) {
      float arr[4], aii[4], wrr[4], wii[4];
      *(float4*)arr = *(const float4*)&Ar[k][ty*4];
      *(float4*)aii = *(const float4*)&Ai[k][ty*4];
      *(float4*)wrr = *(const float4*)&Br_[k][tx*4];
      *(float4*)wii = *(const float4*)&Bi_[k][tx*4];
      #pragma unroll
      for (int im = 0; im < 4; im++)
        #pragma unroll
        for (int jn = 0; jn < 4; jn++) {
          accR[im][jn] += arr[im] * wrr[jn] - aii[im] * wii[jn];
          accI[im][jn] += arr[im] * wii[jn] + aii[im] * wrr[jn];
        }
    }
    __syncthreads();
  }
  #pragma unroll
  for (int im = 0; im < 4; im++) {
    int m = m0 + ty * 4 + im;
    #pragma unroll
    for (int jn = 0; jn < 4; jn++) {
      int j = n0 + tx * 4 + jn;
      float2 o; o.x = accR[im][jn] + br[j]; o.y = accI[im][jn] + bi[j];
      *(float2*)(Y + (size_t)m * T_DIM + j * 2) = o;
    }
  }
}

// ---------------- bf16 MFMA filter scores: S[m][c] = dot(Qn[m], Kn[n_off+c]) ----------------
// 128x128 tile, BK=32, 16x16x32 MFMA, global_load_lds width=16 (m97 structure).
__global__ __launch_bounds__(256)
void mfma_score_kernel(const bf16_t* __restrict__ Qn, const bf16_t* __restrict__ Kn,
                       bf16_t* __restrict__ S, int n_off, int C) {
  __shared__ bf16_t As[128 * 32];   // row-major [128][32], 64B/row
  __shared__ bf16_t Bs[128 * 32];
  int tid = threadIdx.x;
  int lane = tid & 63, wv = tid >> 6;
  int m0 = blockIdx.x * 128;
  int n0 = blockIdx.y * 128;                 // within chunk
  int wm = (wv & 1) * 64, wn = (wv >> 1) * 64;
  f32x4 acc[4][4] = {};
  const bf16_t* Ag = Qn + (size_t)m0 * T_DIM;
  const bf16_t* Bg = Kn + (size_t)(n_off + n0) * T_DIM;
  int frow = lane & 15;
  int fk = (lane >> 4) * 8;
  for (int k0 = 0; k0 < T_DIM; k0 += 32) {
    #pragma unroll
    for (int it = 0; it < 2; it++) {
      int rbase = (it * 4 + wv) * 16;
      int row = rbase + (lane >> 2);
      int gcol = lane & 3;
      const bf16_t* gpa = Ag + (size_t)row * T_DIM + k0 + gcol * 8;
      const bf16_t* gpb = Bg + (size_t)row * T_DIM + k0 + gcol * 8;
      bf16_t* lpa = As + rbase * 32 + lane * 8;
      bf16_t* lpb = Bs + rbase * 32 + lane * 8;
      __builtin_amdgcn_global_load_lds(
          (const __attribute__((address_space(1))) void*)gpa,
          (__attribute__((address_space(3))) void*)lpa, 16, 0, 0);
      __builtin_amdgcn_global_load_lds(
          (const __attribute__((address_space(1))) void*)gpb,
          (__attribute__((address_space(3))) void*)lpb, 16, 0, 0);
    }
    __syncthreads();
    bf16x8 a[4], b[4];
    #pragma unroll
    for (int i = 0; i < 4; i++)
      a[i] = *(const bf16x8*)(As + (wm + i * 16 + frow) * 32 + fk);
    #pragma unroll
    for (int j = 0; j < 4; j++)
      b[j] = *(const bf16x8*)(Bs + (wn + j * 16 + frow) * 32 + fk);
    #pragma unroll
    for (int i = 0; i < 4; i++)
      #pragma unroll
      for (int j = 0; j < 4; j++)
        acc[i][j] = __builtin_amdgcn_mfma_f32_16x16x32_bf16(a[i], b[j], acc[i][j], 0, 0, 0);
    __syncthreads();
  }
  // C/D layout: row = (lane>>4)*4 + reg, col = lane&15  (m89/m91-verified)
  int col = lane & 15, qr = (lane >> 4) * 4;
  #pragma unroll
  for (int i = 0; i < 4; i++)
    #pragma unroll
    for (int j = 0; j < 4; j++) {
      int n = n0 + wn + j * 16 + col;
      #pragma unroll
      for (int r = 0; r < 4; r++) {
        int m = m0 + wm + i * 16 + qr + r;
        S[(size_t)m * C + n] = (bf16_t)acc[i][j][r];
      }
    }
}

// ---------------- exact per-chunk top-128 via two-level histogram threshold ----------------
// Generic over C (multiple of 2048). 3 passes over the row (L2-hot after pass 1):
// coarse hist -> threshold, refined hist on boundary bin -> exact bf16 threshold, collect.
__global__ __launch_bounds__(256)
void select_kernel(const bf16_t* __restrict__ S, int C, int key_off,
                   float* __restrict__ cand_v, int* __restrict__ cand_i,
                   int slot_off, int nslot) {
  int q = blockIdx.x, tid = threadIdx.x;
  __shared__ unsigned hist[NBIN];
  __shared__ unsigned psum[256];
  __shared__ float bv[CAND_SORT];
  __shared__ int bi[CAND_SORT];
  __shared__ unsigned binB_s, cntGt_s, binB2_s, cnt_s;
  const bf16x8* row8 = (const bf16x8*)(S + (size_t)q * C);
  int nvec = C >> 3;

  for (int i = tid; i < NBIN; i += 256) hist[i] = 0;
  if (tid == 0) { cnt_s = 0; binB_s = 0; cntGt_s = 0; binB2_s = 0; }
  __syncthreads();
  // pass 1: coarse histogram (top 11 bits of monotone map)
  for (int v = tid; v < nvec; v += 256) {
    bf16x8 x = row8[v];
    #pragma unroll
    for (int i = 0; i < 8; i++) {
      unsigned t = __float_as_uint((float)x[i]);
      t = (t & 0x80000000u) ? ~t : (t | 0x80000000u);
      atomicAdd(&hist[t >> 21], 1u);
    }
  }
  __syncthreads();
  // suffix scan over 256 groups of 8 bins
  unsigned sgrp = 0;
  #pragma unroll
  for (int b = 0; b < 8; b++) sgrp += hist[tid * 8 + b];
  psum[tid] = sgrp;
  __syncthreads();
  for (int off = 1; off < 256; off <<= 1) {
    unsigned v = psum[tid];
    unsigned add = (tid + off < 256) ? psum[tid + off] : 0u;
    __syncthreads();
    psum[tid] = v + add;
    __syncthreads();
  }
  if (psum[tid] >= (unsigned)K_KEEP && (tid == 255 || psum[tid + 1] < (unsigned)K_KEEP)) {
    unsigned acc = (tid == 255) ? 0u : psum[tid + 1];
    for (int b = tid * 8 + 7; b >= tid * 8; b--) {
      unsigned h = hist[b];
      if (acc + h >= (unsigned)K_KEEP) { binB_s = (unsigned)b; cntGt_s = acc; break; }
      acc += h;
    }
  }
  __syncthreads();
  unsigned B = binB_s;
  unsigned K2 = (unsigned)K_KEEP - cntGt_s;   // >=1 by construction
  for (int i = tid; i < NBIN; i += 256) hist[i] = 0;
  __syncthreads();
  // pass 2: refined histogram on boundary bin (next 11 bits = full bf16 fidelity)
  for (int v = tid; v < nvec; v += 256) {
    bf16x8 x = row8[v];
    #pragma unroll
    for (int i = 0; i < 8; i++) {
      unsigned t = __float_as_uint((float)x[i]);
      t = (t & 0x80000000u) ? ~t : (t | 0x80000000u);
      if ((t >> 21) == B) atomicAdd(&hist[(t >> 10) & 2047u], 1u);
    }
  }
  __syncthreads();
  unsigned sgrp2 = 0;
  #pragma unroll
  for (int b = 0; b < 8; b++) sgrp2 += hist[tid * 8 + b];
  psum[tid] = sgrp2;
  __syncthreads();
  for (int off = 1; off < 256; off <<= 1) {
    unsigned v = psum[tid];
    unsigned add = (tid + off < 256) ? psum[tid + off] : 0u;
    __syncthreads();
    psum[tid] = v + add;
    __syncthreads();
  }
  if (psum[tid] >= K2 && (tid == 255 || psum[tid + 1] < K2)) {
    unsigned acc = (tid == 255) ? 0u : psum[tid + 1];
    for (int b = tid * 8 + 7; b >= tid * 8; b--) {
      unsigned h = hist[b];
      if (acc + h >= K2) { binB2_s = (unsigned)b; break; }
      acc += h;
    }
  }
  __syncthreads();
  unsigned B2 = binB2_s;
  // pass 3: collect (guaranteed >= K_KEEP kept; ties bounded, CAND_SORT=1024 headroom)
  for (int v = tid; v < nvec; v += 256) {
    bf16x8 x = row8[v];
    #pragma unroll
    for (int i = 0; i < 8; i++) {
      float fx = (float)x[i];
      unsigned t = __float_as_uint(fx);
      t = (t & 0x80000000u) ? ~t : (t | 0x80000000u);
      unsigned bin = t >> 21;
      bool keep = (bin > B) || (bin == B && ((t >> 10) & 2047u) >= B2);
      if (keep) {
        unsigned p = atomicAdd(&cnt_s, 1u);
        if (p < (unsigned)CAND_SORT) { bv[p] = fx; bi[p] = key_off + v * 8 + i; }
      }
    }
  }
  __syncthreads();
  int cnt = (int)min(cnt_s, (unsigned)CAND_SORT);
  int n = K_KEEP; while (n < cnt) n <<= 1;
  for (int x = cnt + tid; x < n; x += 256) { bv[x] = -FLT_MAX; bi[x] = 0x7FFFFFFF; }
  for (int k = 2; k <= n; k <<= 1) {
    for (int j = k >> 1; j > 0; j >>= 1) {
      __syncthreads();
      for (int i = tid; i < n; i += 256) {
        int ixj = i ^ j;
        if (ixj > i) {
          float a = bv[i], b = bv[ixj];
          int ia = bi[i], ib = bi[ixj];
          bool a_worse = (a < b) || (a == b && ia > ib);
          bool up = ((i & k) == 0);
          if (up ? a_worse : !a_worse) {
            bv[i] = b; bv[ixj] = a; bi[i] = ib; bi[ixj] = ia;
          }
        }
      }
    }
  }
  __syncthreads();
  if (tid < K_KEEP) {
    cand_v[(size_t)q * nslot + slot_off + tid] = bv[tid];
    cand_i[(size_t)q * nslot + slot_off + tid] = bi[tid];
  }
}

// ---------------- merge per-chunk candidate lists -> global top-128 indices ----------------
__global__ __launch_bounds__(256)
void merge_kernel(const float* __restrict__ cand_v, const int* __restrict__ cand_i,
                  int nslot, int* __restrict__ topi) {
  int q = blockIdx.x, tid = threadIdx.x;
  __shared__ float bv[NBIN];
  __shared__ int bi[NBIN];
  int n = K_KEEP; while (n < nslot) n <<= 1;
  for (int i = tid; i < n; i += 256) {
    if (i < nslot) { bv[i] = cand_v[(size_t)q * nslot + i]; bi[i] = cand_i[(size_t)q * nslot + i]; }
    else { bv[i] = -FLT_MAX; bi[i] = 0x7FFFFFFF; }
  }
  for (int k = 2; k <= n; k <<= 1) {
    for (int j = k >> 1; j > 0; j >>= 1) {
      __syncthreads();
      for (int i = tid; i < n; i += 256) {
        int ixj = i ^ j;
        if (ixj > i) {
          float a = bv[i], b = bv[ixj];
          int ia = bi[i], ib = bi[ixj];
          bool a_worse = (a < b) || (a == b && ia > ib);
          bool up = ((i & k) == 0);
          if (up ? a_worse : !a_worse) {
            bv[i] = b; bv[ixj] = a; bi[i] = ib; bi[ixj] = ia;
          }
        }
      }
    }
  }
  __syncthreads();
  if (tid < K_KEEP) topi[q * K_KEEP + tid] = bi[tid];
}

// ---------------- fp64 exact rescore + top-64 + softmax + gather + phase_norm ----------------
__global__ __launch_bounds__(256)
void rescore_kernel(const int* __restrict__ topi,
                    const double* __restrict__ Qd,
                    const double* __restrict__ qmagd, const double* __restrict__ kmagd,
                    const float* __restrict__ Kk, const float* __restrict__ V,
                    const float* __restrict__ gamma,
                    float* __restrict__ XN) {
  int q = blockIdx.x, tid = threadIdx.x;
  __shared__ double qrow[T_DIM];
  __shared__ double cval[K_KEEP];
  __shared__ int cidx[K_KEEP];
  __shared__ float w[K_TOP];
  __shared__ int widx[K_TOP];
  __shared__ float red[4];
  for (int i = tid; i < T_DIM / 2; i += 256)
    ((double2*)qrow)[i] = ((const double2*)(Qd + (size_t)q * T_DIM))[i];
  if (tid < K_KEEP) cidx[tid] = topi[q * K_KEEP + tid];
  __syncthreads();
  double qm = qmagd[q];
  int wv = tid >> 6, ln = tid & 63;
  #pragma unroll 2
  for (int c = wv; c < K_KEEP; c += 4) {
    int key = cidx[c];
    const float4* kr4 = (const float4*)(Kk + (size_t)key * T_DIM);
    double s = 0.0;
    #pragma unroll
    for (int it = 0; it < 4; it++) {
      float4 v = kr4[ln + it * 64];
      int t = (ln + it * 64) * 4;
      s += (double)v.x * qrow[t]     + (double)v.y * qrow[t + 1]
         + (double)v.z * qrow[t + 2] + (double)v.w * qrow[t + 3];
    }
    for (int o = 32; o > 0; o >>= 1) s += __shfl_down(s, o, 64);
    if (ln == 0) cval[c] = s / (qm * kmagd[key] + EPSD);
  }
  __syncthreads();
  for (int k = 2; k <= K_KEEP; k <<= 1) {
    for (int j = k >> 1; j > 0; j >>= 1) {
      __syncthreads();
      if (tid < K_KEEP) {
        int i = tid, ixj = i ^ j;
        if (ixj > i) {
          double a = cval[i], b = cval[ixj];
          int ia = cidx[i], ib = cidx[ixj];
          bool a_worse = (a < b) || (a == b && ia > ib);
          bool up = ((i & k) == 0);
          if (up ? a_worse : !a_worse) {
            cval[i] = b; cval[ixj] = a; cidx[i] = ib; cidx[ixj] = ia;
          }
        }
      }
    }
  }
  __syncthreads();
  if (tid < 64) {
    double v = cval[tid];
    double m = cval[0];
    double e = exp(v - m);
    double s = e;
    for (int o = 32; o > 0; o >>= 1) s += __shfl_down(s, o, 64);
    s = __shfl(s, 0, 64);
    w[tid] = (float)(e / s);
    widx[tid] = cidx[tid];
  }
  __syncthreads();
  float4 acc = {0.f, 0.f, 0.f, 0.f};
  #pragma unroll 8
  for (int j2 = 0; j2 < 64; j2++) {
    float wj = w[j2];
    float4 v = *(const float4*)(V + (size_t)widx[j2] * T_DIM + tid * 4);
    acc.x += wj * v.x; acc.y += wj * v.y; acc.z += wj * v.z; acc.w += wj * v.w;
  }
  float ls = acc.x*acc.x + acc.y*acc.y + acc.z*acc.z + acc.w*acc.w;
  for (int o = 32; o > 0; o >>= 1) ls += __shfl_down(ls, o, 64);
  if ((tid & 63) == 0) red[tid >> 6] = ls;
  __syncthreads();
  float tot = red[0] + red[1] + red[2] + red[3];
  float rms = sqrtf(tot / (float)D_DIM + EPSF);
  float g0 = gamma[tid * 2] / rms, g1 = gamma[tid * 2 + 1] / rms;
  float4 o = { acc.x * g0, acc.y * g0, acc.z * g1, acc.w * g1 };
  *(float4*)(XN + (size_t)q * T_DIM + tid * 4) = o;
}

extern "C" void kernel_launch(void* const* d_in, const int* in_sizes, int n_in,
                              void* d_out, int out_size, void* d_ws, size_t ws_size,
                              hipStream_t stream) {
  const float* query  = (const float*)d_in[0];
  const float* keys   = (const float*)d_in[1];
  const float* values = (const float*)d_in[2];
  const float* Wq_r   = (const float*)d_in[3];
  const float* Wq_i   = (const float*)d_in[4];
  const float* bq_r   = (const float*)d_in[5];
  const float* bq_i   = (const float*)d_in[6];
  const float* Wo_r   = (const float*)d_in[7];
  const float* Wo_i   = (const float*)d_in[8];
  const float* bo_r   = (const float*)d_in[9];
  const float* bo_i   = (const float*)d_in[10];
  const float* gamma  = (const float*)d_in[11];
  float* out = (float*)d_out;

  int M = in_sizes[0] / T_DIM;   // 4096
  int N = in_sizes[1] / T_DIM;   // 32768

  // fixed-size buffers
  char* ws = (char*)d_ws;
  size_t off = 0;
  double* qd    = (double*)(ws + off); off += (size_t)M * T_DIM * 8;
  float*  xn    = (float*) (ws + off); off += (size_t)M * T_DIM * 4;
  double* qmagd = (double*)(ws + off); off += (size_t)M * 8;
  double* kmagd = (double*)(ws + off); off += (size_t)N * 8;
  int*    topi  = (int*)   (ws + off); off += (size_t)M * K_KEEP * 4;
  bf16_t* qn    = (bf16_t*)(ws + off); off += (size_t)M * T_DIM * 2;
  bf16_t* kn    = (bf16_t*)(ws + off); off += (size_t)N * T_DIM * 2;

  // adaptive chunk width: prefer largest C (fewest launches; C==N avoids real merge work)
  int C = 2048;
  for (int c = N; c >= 2048; c >>= 1) {
    size_t need = off + (size_t)M * c * 2                       // sc (bf16)
                + 2 * (size_t)M * (size_t)(N / c) * K_KEEP * 4; // candv + candi
    if (need <= ws_size) { C = c; break; }
  }
  if (C > N) C = N;
  int nchunks = N / C;
  int nslot = nchunks * K_KEEP;

  bf16_t* sc    = (bf16_t*)(ws + off); off += (size_t)M * C * 2;
  float*  candv = (float*) (ws + off); off += (size_t)M * nslot * 4;
  int*    candi = (int*)   (ws + off); off += (size_t)M * nslot * 4;

  dim3 blk(256);
  cgemm_f64_kernel<<<dim3(M / 64, D_DIM / 64), blk, 0, stream>>>(query, Wq_r, Wq_i, bq_r, bq_i, qd, M);
  rownorm_convert_q_kernel<<<dim3(M), blk, 0, stream>>>(qd, qmagd, qn, M);
  rownorm_convert_k_kernel<<<dim3(N), blk, 0, stream>>>(keys, kmagd, kn, N);
  for (int c = 0; c < nchunks; c++) {
    int noff = c * C;
    mfma_score_kernel<<<dim3(M / 128, C / 128), blk, 0, stream>>>(qn, kn, sc, noff, C);
    select_kernel<<<dim3(M), blk, 0, stream>>>(sc, C, noff, candv, candi, c * K_KEEP, nslot);
  }
  merge_kernel<<<dim3(M), blk, 0, stream>>>(candv, candi, nslot, topi);
  rescore_kernel<<<dim3(M), blk, 0, stream>>>(topi, qd, qmagd, kmagd, keys, values, gamma, xn);
  cgemm_kernel<<<dim3(M / 64, D_DIM / 64), blk, 0, stream>>>(xn, Wo_r, Wo_i, bo_r, bo_i, out, M);
}

// Round 5
// 1825.974 us; speedup vs baseline: 1.5418x; 1.0226x over previous
//
#include <hip/hip_runtime.h>
#include <math.h>
#include <float.h>

#define EPSF 1e-8f
#define EPSD 1e-8
#define D_DIM 512
#define T_DIM 1024   // 2*D (r,i interleaved)
#define K_TOP 64
#define K_KEEP 128
#define NBIN 2048
#define CAND_SORT 1024

typedef __bf16 bf16_t;
typedef __bf16 bf16x8 __attribute__((ext_vector_type(8)));
typedef __bf16 bf16x4 __attribute__((ext_vector_type(4)));
typedef float f32x4 __attribute__((ext_vector_type(4)));

// ---------------- fp64 row magnitude + bf16 normalized copy (q, from fp64 rows) ----------------
__global__ __launch_bounds__(256)
void rownorm_convert_q_kernel(const double* __restrict__ X, double* __restrict__ magd,
                              bf16_t* __restrict__ Qn, int rows) {
  int r = blockIdx.x;
  if (r >= rows) return;
  int tid = threadIdx.x;
  const double* xr = X + (size_t)r * T_DIM;
  double v[4];
  double s = 0.0;
  #pragma unroll
  for (int i = 0; i < 4; i++) { v[i] = xr[tid * 4 + i]; s += v[i] * v[i]; }
  for (int o = 32; o > 0; o >>= 1) s += __shfl_down(s, o, 64);
  __shared__ double red[4];
  __shared__ double mag_s;
  if ((tid & 63) == 0) red[tid >> 6] = s;
  __syncthreads();
  if (tid == 0) {
    double m = sqrt(red[0] + red[1] + red[2] + red[3] + EPSD);
    magd[r] = m; mag_s = m;
  }
  __syncthreads();
  double inv = 1.0 / mag_s;
  bf16x4 o;
  #pragma unroll
  for (int i = 0; i < 4; i++) o[i] = (bf16_t)((float)(v[i] * inv));
  *(bf16x4*)(Qn + (size_t)r * T_DIM + tid * 4) = o;
}

// ---------------- fp64 row magnitude + bf16 normalized copy (keys, from fp32 rows) ----------------
__global__ __launch_bounds__(256)
void rownorm_convert_k_kernel(const float* __restrict__ X, double* __restrict__ magd,
                              bf16_t* __restrict__ Kn, int rows) {
  int r = blockIdx.x;
  if (r >= rows) return;
  int tid = threadIdx.x;
  float4 v = ((const float4*)(X + (size_t)r * T_DIM))[tid];
  double s = (double)v.x * v.x + (double)v.y * v.y + (double)v.z * v.z + (double)v.w * v.w;
  for (int o = 32; o > 0; o >>= 1) s += __shfl_down(s, o, 64);
  __shared__ double red[4];
  __shared__ float inv_s;
  if ((tid & 63) == 0) red[tid >> 6] = s;
  __syncthreads();
  if (tid == 0) {
    double m = sqrt(red[0] + red[1] + red[2] + red[3] + EPSD);
    magd[r] = m; inv_s = (float)(1.0 / m);
  }
  __syncthreads();
  float inv = inv_s;
  bf16x4 o;
  o[0] = (bf16_t)(v.x * inv); o[1] = (bf16_t)(v.y * inv);
  o[2] = (bf16_t)(v.z * inv); o[3] = (bf16_t)(v.w * inv);
  *(bf16x4*)(Kn + (size_t)r * T_DIM + tid * 4) = o;
}

// ---------------- fp64-accumulate complex linear (query projection) ----------------
__global__ __launch_bounds__(256)
void cgemm_f64_kernel(const float* __restrict__ X,
                      const float* __restrict__ Wr, const float* __restrict__ Wi,
                      const float* __restrict__ br, const float* __restrict__ bi,
                      double* __restrict__ Yd, int M) {
  __shared__ float Ar[16][64], Ai[16][64], Br_[16][64], Bi_[16][64];
  int tid = threadIdx.x;
  int tx = tid & 15, ty = tid >> 4;
  int m0 = blockIdx.x * 64, n0 = blockIdx.y * 64;
  double accR[4][4] = {{0}}, accI[4][4] = {{0}};
  for (int k0 = 0; k0 < D_DIM; k0 += 16) {
    #pragma unroll
    for (int gi = 0; gi < 2; gi++) {
      int g = tid + gi * 256;
      int m = g >> 3, dg = g & 7;
      float4 v = *(const float4*)(X + (size_t)(m0 + m) * T_DIM + 2 * k0 + dg * 4);
      Ar[dg*2][m] = v.x; Ai[dg*2][m] = v.y; Ar[dg*2+1][m] = v.z; Ai[dg*2+1][m] = v.w;
    }
    {
      int j = tid >> 2, c = tid & 3;
      float4 vr = *(const float4*)(Wr + (size_t)(n0 + j) * D_DIM + k0 + c * 4);
      float4 vi = *(const float4*)(Wi + (size_t)(n0 + j) * D_DIM + k0 + c * 4);
      Br_[c*4+0][j] = vr.x; Br_[c*4+1][j] = vr.y; Br_[c*4+2][j] = vr.z; Br_[c*4+3][j] = vr.w;
      Bi_[c*4+0][j] = vi.x; Bi_[c*4+1][j] = vi.y; Bi_[c*4+2][j] = vi.z; Bi_[c*4+3][j] = vi.w;
    }
    __syncthreads();
    #pragma unroll
    for (int k = 0; k < 16; k++) {
      float arr[4], aii[4], wrr[4], wii[4];
      *(float4*)arr = *(const float4*)&Ar[k][ty*4];
      *(float4*)aii = *(const float4*)&Ai[k][ty*4];
      *(float4*)wrr = *(const float4*)&Br_[k][tx*4];
      *(float4*)wii = *(const float4*)&Bi_[k][tx*4];
      #pragma unroll
      for (int im = 0; im < 4; im++)
        #pragma unroll
        for (int jn = 0; jn < 4; jn++) {
          double ar = (double)arr[im], ai = (double)aii[im];
          double wr = (double)wrr[jn], wi = (double)wii[jn];
          accR[im][jn] += ar * wr - ai * wi;
          accI[im][jn] += ar * wi + ai * wr;
        }
    }
    __syncthreads();
  }
  #pragma unroll
  for (int im = 0; im < 4; im++) {
    int m = m0 + ty * 4 + im;
    #pragma unroll
    for (int jn = 0; jn < 4; jn++) {
      int j = n0 + tx * 4 + jn;
      size_t base = (size_t)m * T_DIM + j * 2;
      Yd[base]     = accR[im][jn] + (double)br[j];
      Yd[base + 1] = accI[im][jn] + (double)bi[j];
    }
  }
}

// ---------------- fp32 complex linear (output projection) ----------------
__global__ __launch_bounds__(256)
void cgemm_kernel(const float* __restrict__ X,
                  const float* __restrict__ Wr, const float* __restrict__ Wi,
                  const float* __restrict__ br, const float* __restrict__ bi,
                  float* __restrict__ Y, int M) {
  __shared__ float Ar[16][64], Ai[16][64], Br_[16][64], Bi_[16][64];
  int tid = threadIdx.x;
  int tx = tid & 15, ty = tid >> 4;
  int m0 = blockIdx.x * 64, n0 = blockIdx.y * 64;
  float accR[4][4] = {{0}}, accI[4][4] = {{0}};
  for (int k0 = 0; k0 < D_DIM; k0 += 16) {
    #pragma unroll
    for (int gi = 0; gi < 2; gi++) {
      int g = tid + gi * 256;
      int m = g >> 3, dg = g & 7;
      float4 v = *(const float4*)(X + (size_t)(m0 + m) * T_DIM + 2 * k0 + dg * 4);
      Ar[dg*2][m] = v.x; Ai[dg*2][m] = v.y; Ar[dg*2+1][m] = v.z; Ai[dg*2+1][m] = v.w;
    }
    {
      int j = tid >> 2, c = tid & 3;
      float4 vr = *(const float4*)(Wr + (size_t)(n0 + j) * D_DIM + k0 + c * 4);
      float4 vi = *(const float4*)(Wi + (size_t)(n0 + j) * D_DIM + k0 + c * 4);
      Br_[c*4+0][j] = vr.x; Br_[c*4+1][j] = vr.y; Br_[c*4+2][j] = vr.z; Br_[c*4+3][j] = vr.w;
      Bi_[c*4+0][j] = vi.x; Bi_[c*4+1][j] = vi.y; Bi_[c*4+2][j] = vi.z; Bi_[c*4+3][j] = vi.w;
    }
    __syncthreads();
    #pragma unroll
    for (int k = 0; k < 16; k++) {
      float arr[4], aii[4], wrr[4], wii[4];
      *(float4*)arr = *(const float4*)&Ar[k][ty*4];
      *(float4*)aii = *(const float4*)&Ai[k][ty*4];
      *(float4*)wrr = *(const float4*)&Br_[k][tx*4];
      *(float4*)wii = *(const float4*)&Bi_[k][tx*4];
      #pragma unroll
      for (int im = 0; im < 4; im++)
        #pragma unroll
        for (int jn = 0; jn < 4; jn++) {
          accR[im][jn] += arr[im] * wrr[jn] - aii[im] * wii[jn];
          accI[im][jn] += arr[im] * wii[jn] + aii[im] * wrr[jn];
        }
    }
    __syncthreads();
  }
  #pragma unroll
  for (int im = 0; im < 4; im++) {
    int m = m0 + ty * 4 + im;
    #pragma unroll
    for (int jn = 0; jn < 4; jn++) {
      int j = n0 + tx * 4 + jn;
      float2 o; o.x = accR[im][jn] + br[j]; o.y = accI[im][jn] + bi[j];
      *(float2*)(Y + (size_t)m * T_DIM + j * 2) = o;
    }
  }
}

// ---------------- bf16 MFMA filter scores: S[m][c] = dot(Qn[m], Kn[n_off+c]) ----------------
// 128x128 tile, BK=32, 16x16x32 MFMA, global_load_lds width=16 (m97 structure).
// Epilogue: LDS-staged coalesced bf16 stores. XCD-aware bijective block swizzle (m204).
__global__ __launch_bounds__(256)
void mfma_score_kernel(const bf16_t* __restrict__ Qn, const bf16_t* __restrict__ Kn,
                       bf16_t* __restrict__ S, int n_off, int C) {
  __shared__ bf16_t As[128 * 32];   // row-major [128][32], 64B/row
  __shared__ bf16_t Bs[128 * 32];
  __shared__ bf16_t Cs[128 * 128];  // staged output tile
  int tid = threadIdx.x;
  int lane = tid & 63, wv = tid >> 6;
  // XCD-aware bijective swizzle: XCD x owns a contiguous chunk of the remapped space
  int nwg = gridDim.x * gridDim.y;
  int wg = blockIdx.x + blockIdx.y * gridDim.x;
  int q8 = nwg >> 3, r8 = nwg & 7;
  int xcd = wg & 7, sub = wg >> 3;
  int swz = (xcd < r8 ? xcd * (q8 + 1) : r8 * (q8 + 1) + (xcd - r8) * q8) + sub;
  int mt = swz % gridDim.x, nt = swz / gridDim.x;
  int m0 = mt * 128;
  int n0 = nt * 128;                 // within chunk
  int wm = (wv & 1) * 64, wn = (wv >> 1) * 64;
  f32x4 acc[4][4] = {};
  const bf16_t* Ag = Qn + (size_t)m0 * T_DIM;
  const bf16_t* Bg = Kn + (size_t)(n_off + n0) * T_DIM;
  int frow = lane & 15;
  int fk = (lane >> 4) * 8;
  for (int k0 = 0; k0 < T_DIM; k0 += 32) {
    #pragma unroll
    for (int it = 0; it < 2; it++) {
      int rbase = (it * 4 + wv) * 16;
      int row = rbase + (lane >> 2);
      int gcol = lane & 3;
      const bf16_t* gpa = Ag + (size_t)row * T_DIM + k0 + gcol * 8;
      const bf16_t* gpb = Bg + (size_t)row * T_DIM + k0 + gcol * 8;
      bf16_t* lpa = As + rbase * 32 + lane * 8;
      bf16_t* lpb = Bs + rbase * 32 + lane * 8;
      __builtin_amdgcn_global_load_lds(
          (const __attribute__((address_space(1))) void*)gpa,
          (__attribute__((address_space(3))) void*)lpa, 16, 0, 0);
      __builtin_amdgcn_global_load_lds(
          (const __attribute__((address_space(1))) void*)gpb,
          (__attribute__((address_space(3))) void*)lpb, 16, 0, 0);
    }
    __syncthreads();
    bf16x8 a[4], b[4];
    #pragma unroll
    for (int i = 0; i < 4; i++)
      a[i] = *(const bf16x8*)(As + (wm + i * 16 + frow) * 32 + fk);
    #pragma unroll
    for (int j = 0; j < 4; j++)
      b[j] = *(const bf16x8*)(Bs + (wn + j * 16 + frow) * 32 + fk);
    #pragma unroll
    for (int i = 0; i < 4; i++)
      #pragma unroll
      for (int j = 0; j < 4; j++)
        acc[i][j] = __builtin_amdgcn_mfma_f32_16x16x32_bf16(a[i], b[j], acc[i][j], 0, 0, 0);
    __syncthreads();
  }
  // C/D layout: row = (lane>>4)*4 + reg, col = lane&15  (m89/m91-verified)
  int col = lane & 15, qr = (lane >> 4) * 4;
  #pragma unroll
  for (int i = 0; i < 4; i++)
    #pragma unroll
    for (int j = 0; j < 4; j++)
      #pragma unroll
      for (int r = 0; r < 4; r++)
        Cs[(wm + i * 16 + qr + r) * 128 + (wn + j * 16 + col)] = (bf16_t)acc[i][j][r];
  __syncthreads();
  // coalesced write-out: 128 rows x 256B, 16B per thread per iter
  const float4* cs4 = (const float4*)Cs;
  #pragma unroll
  for (int it = 0; it < 8; it++) {
    int idx = it * 256 + tid;          // 0..2047
    int row = idx >> 4;
    int cb  = idx & 15;
    *(float4*)((char*)S + ((size_t)(m0 + row) * C + n0) * 2 + cb * 16) = cs4[idx];
  }
}

// ---------------- exact per-row top-128 via max-anchored ulp-level histogram ----------------
// Pass A: row-max 16-bit key. Pass B: fine histogram over the 2048-ulp window below max
// (values below window skipped -> no atomic hot-spot), suffix-scan -> exact bf16 threshold.
// Pass C: collect >= thr (~128+ties), small bitonic sort, emit top-128.
__global__ __launch_bounds__(256)
void select_kernel(const bf16_t* __restrict__ S, int C, int key_off,
                   float* __restrict__ cand_v, int* __restrict__ cand_i,
                   int slot_off, int nslot) {
  int q = blockIdx.x, tid = threadIdx.x;
  __shared__ unsigned hist[NBIN];
  __shared__ unsigned psum[256];
  __shared__ unsigned redmax[4];
  __shared__ float bv[CAND_SORT];
  __shared__ int bi[CAND_SORT];
  __shared__ unsigned thr_s, cnt_s;
  const bf16x8* row8 = (const bf16x8*)(S + (size_t)q * C);
  int nvec = C >> 3;

  // pass A: exact row max of monotone 16-bit keys
  unsigned kmax = 0;
  for (int v = tid; v < nvec; v += 256) {
    bf16x8 x = row8[v];
    #pragma unroll
    for (int i = 0; i < 8; i++) {
      unsigned t = __float_as_uint((float)x[i]);
      t = (t & 0x80000000u) ? ~t : (t | 0x80000000u);
      unsigned k = t >> 16;
      kmax = kmax > k ? kmax : k;
    }
  }
  for (int o = 32; o > 0; o >>= 1) {
    unsigned other = (unsigned)__shfl_down((int)kmax, o, 64);
    kmax = kmax > other ? kmax : other;
  }
  if ((tid & 63) == 0) redmax[tid >> 6] = kmax;
  __syncthreads();
  unsigned rm01 = redmax[0] > redmax[1] ? redmax[0] : redmax[1];
  unsigned rm23 = redmax[2] > redmax[3] ? redmax[2] : redmax[3];
  unsigned rowmax = rm01 > rm23 ? rm01 : rm23;

  // pass B (looped only for pathological distributions): windowed ulp histogram
  unsigned base = rowmax >= (unsigned)(NBIN - 1) ? rowmax - (unsigned)(NBIN - 1) : 0u;
  unsigned cntAbove = 0;
  unsigned thr = 0;
  while (true) {
    for (int i = tid; i < NBIN; i += 256) hist[i] = 0;
    __syncthreads();
    for (int v = tid; v < nvec; v += 256) {
      bf16x8 x = row8[v];
      #pragma unroll
      for (int i = 0; i < 8; i++) {
        unsigned t = __float_as_uint((float)x[i]);
        t = (t & 0x80000000u) ? ~t : (t | 0x80000000u);
        unsigned d = (t >> 16) - base;     // wraps large if below window
        if (d < (unsigned)NBIN) atomicAdd(&hist[d], 1u);
      }
    }
    __syncthreads();
    unsigned sg = 0;
    #pragma unroll
    for (int b = 0; b < 8; b++) sg += hist[tid * 8 + b];
    psum[tid] = sg;
    __syncthreads();
    for (int off = 1; off < 256; off <<= 1) {
      unsigned v0 = psum[tid];
      unsigned ad = (tid + off < 256) ? psum[tid + off] : 0u;
      __syncthreads();
      psum[tid] = v0 + ad;
      __syncthreads();
    }
    unsigned K2 = (unsigned)K_KEEP - cntAbove;
    unsigned total = psum[0];
    if (total >= K2) {
      if (psum[tid] >= K2 && (tid == 255 || psum[tid + 1] < K2)) {
        unsigned acc = (tid == 255) ? 0u : psum[tid + 1];
        for (int b = tid * 8 + 7; b >= tid * 8; b--) {
          acc += hist[b];
          if (acc >= K2) { thr_s = base + (unsigned)b; break; }
        }
      }
      __syncthreads();
      thr = thr_s;
      break;
    }
    cntAbove += total;
    if (base == 0) { thr = 0; break; }
    base = base >= (unsigned)NBIN ? base - (unsigned)NBIN : 0u;
    __syncthreads();   // protect psum[0] reads before hist re-zeroing
  }

  // pass C: collect all values with key >= thr
  if (tid == 0) cnt_s = 0;
  __syncthreads();
  for (int v = tid; v < nvec; v += 256) {
    bf16x8 x = row8[v];
    #pragma unroll
    for (int i = 0; i < 8; i++) {
      float fx = (float)x[i];
      unsigned t = __float_as_uint(fx);
      t = (t & 0x80000000u) ? ~t : (t | 0x80000000u);
      if ((t >> 16) >= thr) {
        unsigned p = atomicAdd(&cnt_s, 1u);
        if (p < (unsigned)CAND_SORT) { bv[p] = fx; bi[p] = key_off + v * 8 + i; }
      }
    }
  }
  __syncthreads();
  int cnt = (int)min(cnt_s, (unsigned)CAND_SORT);
  int n = K_KEEP; while (n < cnt) n <<= 1;
  for (int x = cnt + tid; x < n; x += 256) { bv[x] = -FLT_MAX; bi[x] = 0x7FFFFFFF; }
  for (int k = 2; k <= n; k <<= 1) {
    for (int j = k >> 1; j > 0; j >>= 1) {
      __syncthreads();
      for (int i = tid; i < n; i += 256) {
        int ixj = i ^ j;
        if (ixj > i) {
          float a = bv[i], b = bv[ixj];
          int ia = bi[i], ib = bi[ixj];
          bool a_worse = (a < b) || (a == b && ia > ib);
          bool up = ((i & k) == 0);
          if (up ? a_worse : !a_worse) {
            bv[i] = b; bv[ixj] = a; bi[i] = ib; bi[ixj] = ia;
          }
        }
      }
    }
  }
  __syncthreads();
  if (tid < K_KEEP) {
    cand_v[(size_t)q * nslot + slot_off + tid] = bv[tid];
    cand_i[(size_t)q * nslot + slot_off + tid] = bi[tid];
  }
}

// ---------------- merge per-chunk candidate lists -> global top-128 indices ----------------
__global__ __launch_bounds__(256)
void merge_kernel(const float* __restrict__ cand_v, const int* __restrict__ cand_i,
                  int nslot, int* __restrict__ topi) {
  int q = blockIdx.x, tid = threadIdx.x;
  __shared__ float bv[NBIN];
  __shared__ int bi[NBIN];
  int n = K_KEEP; while (n < nslot) n <<= 1;
  for (int i = tid; i < n; i += 256) {
    if (i < nslot) { bv[i] = cand_v[(size_t)q * nslot + i]; bi[i] = cand_i[(size_t)q * nslot + i]; }
    else { bv[i] = -FLT_MAX; bi[i] = 0x7FFFFFFF; }
  }
  for (int k = 2; k <= n; k <<= 1) {
    for (int j = k >> 1; j > 0; j >>= 1) {
      __syncthreads();
      for (int i = tid; i < n; i += 256) {
        int ixj = i ^ j;
        if (ixj > i) {
          float a = bv[i], b = bv[ixj];
          int ia = bi[i], ib = bi[ixj];
          bool a_worse = (a < b) || (a == b && ia > ib);
          bool up = ((i & k) == 0);
          if (up ? a_worse : !a_worse) {
            bv[i] = b; bv[ixj] = a; bi[i] = ib; bi[ixj] = ia;
          }
        }
      }
    }
  }
  __syncthreads();
  if (tid < K_KEEP) topi[q * K_KEEP + tid] = bi[tid];
}

// ---------------- fp64 exact rescore + top-64 + softmax + gather + phase_norm ----------------
__global__ __launch_bounds__(256)
void rescore_kernel(const int* __restrict__ topi,
                    const double* __restrict__ Qd,
                    const double* __restrict__ qmagd, const double* __restrict__ kmagd,
                    const float* __restrict__ Kk, const float* __restrict__ V,
                    const float* __restrict__ gamma,
                    float* __restrict__ XN) {
  int q = blockIdx.x, tid = threadIdx.x;
  __shared__ double qrow[T_DIM];
  __shared__ double cval[K_KEEP];
  __shared__ int cidx[K_KEEP];
  __shared__ float w[K_TOP];
  __shared__ int widx[K_TOP];
  __shared__ float red[4];
  for (int i = tid; i < T_DIM / 2; i += 256)
    ((double2*)qrow)[i] = ((const double2*)(Qd + (size_t)q * T_DIM))[i];
  if (tid < K_KEEP) cidx[tid] = topi[q * K_KEEP + tid];
  __syncthreads();
  double qm = qmagd[q];
  int wv = tid >> 6, ln = tid & 63;
  // 2 key-rows in flight per wave: 8 outstanding loads, shared qrow reads
  for (int c = wv; c < K_KEEP; c += 8) {
    int keyA = cidx[c];
    int keyB = cidx[c + 4];
    const float4* A4 = (const float4*)(Kk + (size_t)keyA * T_DIM);
    const float4* B4 = (const float4*)(Kk + (size_t)keyB * T_DIM);
    double sA = 0.0, sB = 0.0;
    #pragma unroll
    for (int it = 0; it < 4; it++) {
      float4 va = A4[ln + it * 64];
      float4 vb = B4[ln + it * 64];
      int t = (ln + it * 64) * 4;
      double q0 = qrow[t], q1 = qrow[t + 1], q2 = qrow[t + 2], q3 = qrow[t + 3];
      sA += (double)va.x * q0 + (double)va.y * q1 + (double)va.z * q2 + (double)va.w * q3;
      sB += (double)vb.x * q0 + (double)vb.y * q1 + (double)vb.z * q2 + (double)vb.w * q3;
    }
    for (int o = 32; o > 0; o >>= 1) {
      sA += __shfl_down(sA, o, 64);
      sB += __shfl_down(sB, o, 64);
    }
    if (ln == 0) {
      cval[c]     = sA / (qm * kmagd[keyA] + EPSD);
      cval[c + 4] = sB / (qm * kmagd[keyB] + EPSD);
    }
  }
  __syncthreads();
  for (int k = 2; k <= K_KEEP; k <<= 1) {
    for (int j = k >> 1; j > 0; j >>= 1) {
      __syncthreads();
      if (tid < K_KEEP) {
        int i = tid, ixj = i ^ j;
        if (ixj > i) {
          double a = cval[i], b = cval[ixj];
          int ia = cidx[i], ib = cidx[ixj];
          bool a_worse = (a < b) || (a == b && ia > ib);
          bool up = ((i & k) == 0);
          if (up ? a_worse : !a_worse) {
            cval[i] = b; cval[ixj] = a; cidx[i] = ib; cidx[ixj] = ia;
          }
        }
      }
    }
  }
  __syncthreads();
  if (tid < 64) {
    double v = cval[tid];
    double m = cval[0];
    double e = exp(v - m);
    double s = e;
    for (int o = 32; o > 0; o >>= 1) s += __shfl_down(s, o, 64);
    s = __shfl(s, 0, 64);
    w[tid] = (float)(e / s);
    widx[tid] = cidx[tid];
  }
  __syncthreads();
  float4 acc = {0.f, 0.f, 0.f, 0.f};
  #pragma unroll 8
  for (int j2 = 0; j2 < 64; j2++) {
    float wj = w[j2];
    float4 v = *(const float4*)(V + (size_t)widx[j2] * T_DIM + tid * 4);
    acc.x += wj * v.x; acc.y += wj * v.y; acc.z += wj * v.z; acc.w += wj * v.w;
  }
  float ls = acc.x*acc.x + acc.y*acc.y + acc.z*acc.z + acc.w*acc.w;
  for (int o = 32; o > 0; o >>= 1) ls += __shfl_down(ls, o, 64);
  if ((tid & 63) == 0) red[tid >> 6] = ls;
  __syncthreads();
  float tot = red[0] + red[1] + red[2] + red[3];
  float rms = sqrtf(tot / (float)D_DIM + EPSF);
  float g0 = gamma[tid * 2] / rms, g1 = gamma[tid * 2 + 1] / rms;
  float4 o = { acc.x * g0, acc.y * g0, acc.z * g1, acc.w * g1 };
  *(float4*)(XN + (size_t)q * T_DIM + tid * 4) = o;
}

extern "C" void kernel_launch(void* const* d_in, const int* in_sizes, int n_in,
                              void* d_out, int out_size, void* d_ws, size_t ws_size,
                              hipStream_t stream) {
  const float* query  = (const float*)d_in[0];
  const float* keys   = (const float*)d_in[1];
  const float* values = (const float*)d_in[2];
  const float* Wq_r   = (const float*)d_in[3];
  const float* Wq_i   = (const float*)d_in[4];
  const float* bq_r   = (const float*)d_in[5];
  const float* bq_i   = (const float*)d_in[6];
  const float* Wo_r   = (const float*)d_in[7];
  const float* Wo_i   = (const float*)d_in[8];
  const float* bo_r   = (const float*)d_in[9];
  const float* bo_i   = (const float*)d_in[10];
  const float* gamma  = (const float*)d_in[11];
  float* out = (float*)d_out;

  int M = in_sizes[0] / T_DIM;   // 4096
  int N = in_sizes[1] / T_DIM;   // 32768

  // fixed-size buffers
  char* ws = (char*)d_ws;
  size_t off = 0;
  double* qd    = (double*)(ws + off); off += (size_t)M * T_DIM * 8;
  float*  xn    = (float*) (ws + off); off += (size_t)M * T_DIM * 4;
  double* qmagd = (double*)(ws + off); off += (size_t)M * 8;
  double* kmagd = (double*)(ws + off); off += (size_t)N * 8;
  int*    topi  = (int*)   (ws + off); off += (size_t)M * K_KEEP * 4;
  bf16_t* qn    = (bf16_t*)(ws + off); off += (size_t)M * T_DIM * 2;
  bf16_t* kn    = (bf16_t*)(ws + off); off += (size_t)N * T_DIM * 2;

  // adaptive chunk width: prefer largest C (fewest launches; C==N avoids merge entirely)
  int C = 2048;
  for (int c = N; c >= 2048; c >>= 1) {
    size_t need = off + (size_t)M * c * 2                       // sc (bf16)
                + 2 * (size_t)M * (size_t)(N / c) * K_KEEP * 4; // candv + candi
    if (need <= ws_size) { C = c; break; }
  }
  if (C > N) C = N;
  int nchunks = N / C;
  int nslot = nchunks * K_KEEP;

  bf16_t* sc    = (bf16_t*)(ws + off); off += (size_t)M * C * 2;
  float*  candv = (float*) (ws + off); off += (size_t)M * nslot * 4;
  int*    candi = (int*)   (ws + off); off += (size_t)M * nslot * 4;

  dim3 blk(256);
  cgemm_f64_kernel<<<dim3(M / 64, D_DIM / 64), blk, 0, stream>>>(query, Wq_r, Wq_i, bq_r, bq_i, qd, M);
  rownorm_convert_q_kernel<<<dim3(M), blk, 0, stream>>>(qd, qmagd, qn, M);
  rownorm_convert_k_kernel<<<dim3(N), blk, 0, stream>>>(keys, kmagd, kn, N);
  for (int c = 0; c < nchunks; c++) {
    int noff = c * C;
    mfma_score_kernel<<<dim3(M / 128, C / 128), blk, 0, stream>>>(qn, kn, sc, noff, C);
    select_kernel<<<dim3(M), blk, 0, stream>>>(sc, C, noff, candv, candi, c * K_KEEP, nslot);
  }
  const int* top_src = candi;
  if (nchunks > 1) {
    merge_kernel<<<dim3(M), blk, 0, stream>>>(candv, candi, nslot, topi);
    top_src = topi;
  }
  rescore_kernel<<<dim3(M), blk, 0, stream>>>(top_src, qd, qmagd, kmagd, keys, values, gamma, xn);
  cgemm_kernel<<<dim3(M / 64, D_DIM / 64), blk, 0, stream>>>(xn, Wo_r, Wo_i, bo_r, bo_i, out, M);
}